// Round 13
// baseline (220.263 us; speedup 1.0000x reference)
//
#include <hip/hip_runtime.h>

#define N_TOK 2048
#define DD 512
#define FF 512
#define EE 64
#define TK 6
#define NG 66
#define RSLOT 12288   // N_TOK*TK
#define NSLOT 16384   // RSLOT + 2*N_TOK
#define BM 64
#define BN 64
#define NKT2 16       // 512/32 k-tiles (BK=32)
#define MAXT 320
#define MATSZ 262144  // 512*512

typedef float f32x4 __attribute__((ext_vector_type(4)));
typedef __bf16 bf16x8 __attribute__((ext_vector_type(8)));

__device__ __forceinline__ unsigned cvtpk(float lo, float hi) {
  unsigned r;
  asm("v_cvt_pk_bf16_f32 %0, %1, %2" : "=v"(r) : "v"(lo), "v"(hi));
  return r;
}

// balanced 2-bit row swizzle: rows map 2-way-balanced onto bank slots
__device__ __forceinline__ int swz4(int r) { return (r + (r >> 2)) & 3; }

// async global->LDS DMA, 16B/lane; dest = wave-uniform base + lane*16
__device__ __forceinline__ void gll16(const void* g, void* l) {
  __builtin_amdgcn_global_load_lds(
      (const __attribute__((address_space(1))) unsigned int*)g,
      (__attribute__((address_space(3))) unsigned int*)l, 16, 0, 0);
}

__device__ __forceinline__ void fence_barrier() {
  asm volatile("" ::: "memory");
  __builtin_amdgcn_s_barrier();
  __builtin_amdgcn_sched_barrier(0);
}

// ------- convert+transpose weights via LDS (r12, at mixed-stream BW ceiling) ----
__global__ __launch_bounds__(256) void convw_k(
    const float* __restrict__ Wg, const float* __restrict__ Wu, const float* __restrict__ Wd,
    const float* __restrict__ sWg, const float* __restrict__ sWu, const float* __restrict__ sWd,
    short* __restrict__ Wt) {
  __shared__ float T[64][33];
  int y = blockIdx.y;
  int kind = y / 66, idx = y % 66;
  const float* src;
  if (kind == 0)      src = (idx < EE) ? Wg + (size_t)idx * MATSZ : sWg + (size_t)(idx - EE) * MATSZ;
  else if (kind == 1) src = (idx < EE) ? Wu + (size_t)idx * MATSZ : sWu + (size_t)(idx - EE) * MATSZ;
  else                src = (idx < EE) ? Wd + (size_t)idx * MATSZ : sWd + (size_t)(idx - EE) * MATSZ;
  short* dst = Wt + (size_t)y * MATSZ;
  int d0 = (blockIdx.x & 7) * 64;
  int f0 = (blockIdx.x >> 3) * 32;
  int t = threadIdx.x;

  int r = t >> 3, fo = (t & 7) * 4;
  const float* sp = src + (size_t)(d0 + r) * 512 + f0 + fo;
  *(f32x4*)&T[r][fo]      = *(const f32x4*)sp;
  *(f32x4*)&T[r + 32][fo] = *(const f32x4*)(sp + (size_t)32 * 512);
  __syncthreads();

  int f = t >> 3, a = t & 7, dd = a * 8;
  float v[8];
#pragma unroll
  for (int i = 0; i < 8; ++i) v[i] = T[dd + i][f];
  uint4 o;
  o.x = cvtpk(v[0], v[1]); o.y = cvtpk(v[2], v[3]);
  o.z = cvtpk(v[4], v[5]); o.w = cvtpk(v[6], v[7]);
  *(uint4*)&dst[(size_t)(f0 + f) * 512 + d0 + dd] = o;
}

// ------- convert X f32 -> bf16
__global__ void convx_k(const float* __restrict__ x, short* __restrict__ Xb) {
  int i = blockIdx.x * 256 + threadIdx.x;
  const f32x4* p = (const f32x4*)(x + (size_t)i * 8);
  f32x4 v0 = p[0], v1 = p[1];
  uint4 o;
  o.x = cvtpk(v0[0], v0[1]); o.y = cvtpk(v0[2], v0[3]);
  o.z = cvtpk(v1[0], v1[1]); o.w = cvtpk(v1[2], v1[3]);
  *(uint4*)&Xb[(size_t)i * 8] = o;
}

// ---------------- router ----------------
__global__ __launch_bounds__(256) void router_k(
    const float* __restrict__ x, const float* __restrict__ Wr,
    int* __restrict__ top_i, float* __restrict__ top_w, int* __restrict__ cnt) {
  __shared__ float xs[16 * 512];
  __shared__ float part[4][16][64];
  int tid = threadIdx.x, lane = tid & 63, w = tid >> 6;
  int t0 = blockIdx.x * 16;
  const f32x4* xin = (const f32x4*)(x + (size_t)t0 * DD);
  f32x4* xs4 = (f32x4*)xs;
#pragma unroll
  for (int i = 0; i < 8; ++i) xs4[i * 256 + tid] = xin[i * 256 + tid];
  __syncthreads();
  float acc[16];
#pragma unroll
  for (int t = 0; t < 16; ++t) acc[t] = 0.f;
  for (int kk = 0; kk < 32; ++kk) {
    int k = w * 128 + kk * 4;
    float w0 = Wr[(size_t)(k + 0) * EE + lane];
    float w1 = Wr[(size_t)(k + 1) * EE + lane];
    float w2 = Wr[(size_t)(k + 2) * EE + lane];
    float w3 = Wr[(size_t)(k + 3) * EE + lane];
#pragma unroll
    for (int t = 0; t < 16; ++t) {
      f32x4 xv = *(const f32x4*)&xs[t * 512 + k];
      acc[t] = fmaf(xv[0], w0, acc[t]);
      acc[t] = fmaf(xv[1], w1, acc[t]);
      acc[t] = fmaf(xv[2], w2, acc[t]);
      acc[t] = fmaf(xv[3], w3, acc[t]);
    }
  }
#pragma unroll
  for (int t = 0; t < 16; ++t) part[w][t][lane] = acc[t];
  __syncthreads();
#pragma unroll
  for (int tt = 0; tt < 4; ++tt) {
    int t = w * 4 + tt;
    float l0 = part[0][t][lane] + part[1][t][lane] + part[2][t][lane] + part[3][t][lane];
    float m = l0;
#pragma unroll
    for (int s = 32; s; s >>= 1) m = fmaxf(m, __shfl_xor(m, s));
    float p = __expf(l0 - m);
    int wi[TK]; float wv[TK];
#pragma unroll
    for (int it = 0; it < TK; ++it) {
      float v = p;
#pragma unroll
      for (int s = 32; s; s >>= 1) v = fmaxf(v, __shfl_xor(v, s));
      unsigned long long b = __ballot(p == v);
      int idx = __ffsll((unsigned long long)b) - 1;
      wi[it] = idx; wv[it] = v;
      if (lane == idx) p = -1.f;
    }
    float wsum = 0.f;
#pragma unroll
    for (int it = 0; it < TK; ++it) wsum += wv[it];
    int tg = t0 + t;
    if (lane < TK) {
      int si = 0; float sv = 0.f;
#pragma unroll
      for (int it = 0; it < TK; ++it) if (lane == it) { si = wi[it]; sv = wv[it]; }
      top_i[tg * TK + lane] = si;
      top_w[tg * TK + lane] = sv / wsum;
      atomicAdd(&cnt[si], 1);
    }
  }
}

// ---------------- offsets + dense work list ----------------
__global__ void offsets_k(const int* __restrict__ cnt, int* __restrict__ goff,
                          int* __restrict__ fill, int* __restrict__ wk_g,
                          int* __restrict__ wk_mt, int* __restrict__ nitems) {
  int i = threadIdx.x;  // 0..63
  fill[i] = 0;
  int c = cnt[i];
  int s = c;
#pragma unroll
  for (int d = 1; d < 64; d <<= 1) { int t = __shfl_up(s, d); if (i >= d) s += t; }
  goff[i] = s - c;
  if (i == 63) {
    goff[EE] = RSLOT;
    goff[EE + 1] = RSLOT + N_TOK;
    goff[EE + 2] = RSLOT + 2 * N_TOK;
  }
  int nt = (c + BM - 1) >> 6;
  int ts = nt;
#pragma unroll
  for (int d = 1; d < 64; d <<= 1) { int t = __shfl_up(ts, d); if (i >= d) ts += t; }
  int texcl = ts - nt;
  for (int t = 0; t < nt; ++t) { wk_g[texcl + t] = i; wk_mt[texcl + t] = t; }
  int tot = __shfl(ts, 63);
  wk_g[tot + i] = EE + (i >> 5);
  wk_mt[tot + i] = i & 31;
  if (i == 0) nitems[0] = tot + 64;
}

// ---------------- scatter (also builds token->slot inverse map) ----------------
__global__ void scatter_k(const int* __restrict__ top_i, const float* __restrict__ top_w,
                          const int* __restrict__ goff, int* __restrict__ fill,
                          int* __restrict__ btok, float* __restrict__ bw,
                          int* __restrict__ tslot) {
  int idx = blockIdx.x * blockDim.x + threadIdx.x;
  if (idx < RSLOT) {
    int e = top_i[idx];
    int pos = goff[e] + atomicAdd(&fill[e], 1);
    btok[pos] = idx / TK;
    bw[pos] = top_w[idx];
    tslot[idx] = pos;
  } else if (idx < NSLOT) {
    int j = idx - RSLOT;
    btok[idx] = j & (N_TOK - 1);
    bw[idx] = 1.0f;
  }
}

// -------- GEMM1: H = silu(Xb*Wg)*(Xb*Wu). BK=32, dbuf 2x12KB, counted-wait loop.
__global__ __launch_bounds__(256) void gemm1_k(
    const short* __restrict__ Xb, const short* __restrict__ Wtg, const short* __restrict__ Wtu,
    const int* __restrict__ goff, const int* __restrict__ btok,
    const int* __restrict__ wk_g, const int* __restrict__ wk_mt,
    const int* __restrict__ nitems, short* __restrict__ H) {
  int item = blockIdx.y;
  if (item >= nitems[0]) return;
  int g = wk_g[item], mt = wk_mt[item];
  int s0g = goff[g], cnt = goff[g + 1] - s0g;
  int n0 = blockIdx.x * BN;
  const short* gmat = Wtg + (size_t)g * MATSZ;
  const short* umat = Wtu + (size_t)g * MATSZ;

  // per buffer (shorts): A [0,2048) 64 rows x 32k; G [2048,4096); U [4096,6144)
  __shared__ __align__(16) short lds[2][6144];   // 24 KB

  int tid = threadIdx.x, lane = tid & 63, w = tid >> 6;
  int wr = w >> 1, wc = w & 1;
  int lr = lane & 15, lgq = lane >> 4;
  int s0 = s0g + mt * BM;

  // staging: 12 chunks of 1KB/buf; wave w owns chunks w*3..w*3+2
  const short* sp[3];
  int ldst[3];
#pragma unroll
  for (int q = 0; q < 3; ++q) {
    int c = w * 3 + q;
    int mat = c >> 2, cc = c & 3;
    ldst[q] = mat * 2048 + cc * 512;
    int rl = cc * 16 + (lane >> 2);        // tile row 0..63
    int gu = (lane & 3) ^ swz4(rl);        // swizzled 16B unit within 64B row
    if (mat == 0) {
      int slot = (mt * BM + rl < cnt) ? s0 + rl : s0;
      sp[q] = Xb + (size_t)btok[slot] * 512 + gu * 8;
    } else if (mat == 1) {
      sp[q] = gmat + (size_t)(n0 + rl) * 512 + gu * 8;
    } else {
      sp[q] = umat + (size_t)(n0 + rl) * 512 + gu * 8;
    }
  }

  f32x4 accg[2][2], accu[2][2];
#pragma unroll
  for (int i = 0; i < 2; ++i)
#pragma unroll
    for (int j = 0; j < 2; ++j) {
      accg[i][j] = f32x4{0.f, 0.f, 0.f, 0.f};
      accu[i][j] = f32x4{0.f, 0.f, 0.f, 0.f};
    }

  auto STAGE = [&](int b, int kt) {
#pragma unroll
    for (int q = 0; q < 3; ++q) gll16(sp[q] + kt * 32, &lds[b][ldst[q]]);
  };
  auto COMPUTE = [&](int b) {
    const short* L = lds[b];
    bf16x8 af[2], bg[2], bu[2];
#pragma unroll
    for (int i = 0; i < 2; ++i) {
      int row = wr * 32 + i * 16 + lr;
      af[i] = *(const bf16x8*)&L[row * 32 + ((lgq ^ swz4(row)) * 8)];
    }
#pragma unroll
    for (int j = 0; j < 2; ++j) {
      int fr = wc * 32 + j * 16 + lr;
      int o = fr * 32 + ((lgq ^ swz4(fr)) * 8);
      bg[j] = *(const bf16x8*)&L[2048 + o];
      bu[j] = *(const bf16x8*)&L[4096 + o];
    }
#pragma unroll
    for (int i = 0; i < 2; ++i)
#pragma unroll
      for (int j = 0; j < 2; ++j) {
        accg[i][j] = __builtin_amdgcn_mfma_f32_16x16x32_bf16(af[i], bg[j], accg[i][j], 0, 0, 0);
        accu[i][j] = __builtin_amdgcn_mfma_f32_16x16x32_bf16(af[i], bu[j], accu[i][j], 0, 0, 0);
      }
  };

  STAGE(0, 0);
  asm volatile("s_waitcnt vmcnt(0)" ::: "memory");
  fence_barrier();
#pragma unroll 1
  for (int kt = 0; kt < NKT2; ++kt) {
    int cur = kt & 1;
    if (kt + 1 < NKT2) STAGE(cur ^ 1, kt + 1);
    COMPUTE(cur);
    if (kt + 1 < NKT2) asm volatile("s_waitcnt vmcnt(0)" ::: "memory");
    fence_barrier();
  }

#pragma unroll
  for (int i = 0; i < 2; ++i)
#pragma unroll
    for (int j = 0; j < 2; ++j)
#pragma unroll
      for (int r = 0; r < 4; ++r) {
        int mrow = wr * 32 + i * 16 + lgq * 4 + r;
        if (mt * BM + mrow < cnt) {
          float gg = accg[i][j][r];
          float uu = accu[i][j][r];
          float hv = (gg / (1.f + __expf(-gg))) * uu;
          int col = n0 + wc * 32 + j * 16 + lr;
          H[(size_t)(s0 + mrow) * FF + col] = (short)(cvtpk(hv, hv) & 0xffffu);
        }
      }
}

// -------- GEMM2: Osl[slot] = bw[slot]*(H[slot] x Wtd_g). BK=32, dbuf 2x8KB. ----
__global__ __launch_bounds__(256) void gemm2_k(
    const short* __restrict__ H, const short* __restrict__ Wtd,
    const int* __restrict__ goff, const float* __restrict__ bw,
    const int* __restrict__ wk_g, const int* __restrict__ wk_mt,
    const int* __restrict__ nitems, short* __restrict__ Osl) {
  int item = blockIdx.y;
  if (item >= nitems[0]) return;
  int g = wk_g[item], mt = wk_mt[item];
  int s0g = goff[g], cnt = goff[g + 1] - s0g;
  int n0 = blockIdx.x * BN;
  const short* dmat = Wtd + (size_t)g * MATSZ;

  // per buffer (shorts): A(H) [0,2048); B(Wtd) [2048,4096)
  __shared__ __align__(16) short lds[2][4096];   // 16 KB

  int tid = threadIdx.x, lane = tid & 63, w = tid >> 6;
  int wr = w >> 1, wc = w & 1;
  int lr = lane & 15, lgq = lane >> 4;
  int s0 = s0g + mt * BM;

  const short* sp[2];
  int ldst[2];
#pragma unroll
  for (int q = 0; q < 2; ++q) {
    int c = w * 2 + q;                 // 0..7
    int mat = c >> 2, cc = c & 3;
    ldst[q] = mat * 2048 + cc * 512;
    int rl = cc * 16 + (lane >> 2);
    int gu = (lane & 3) ^ swz4(rl);
    if (mat == 0) {
      int slot = (mt * BM + rl < cnt) ? s0 + rl : s0;
      sp[q] = H + (size_t)slot * 512 + gu * 8;
    } else {
      sp[q] = dmat + (size_t)(n0 + rl) * 512 + gu * 8;
    }
  }

  f32x4 acc[2][2];
#pragma unroll
  for (int i = 0; i < 2; ++i)
#pragma unroll
    for (int j = 0; j < 2; ++j) acc[i][j] = f32x4{0.f, 0.f, 0.f, 0.f};

  auto STAGE = [&](int b, int kt) {
#pragma unroll
    for (int q = 0; q < 2; ++q) gll16(sp[q] + kt * 32, &lds[b][ldst[q]]);
  };
  auto COMPUTE = [&](int b) {
    const short* L = lds[b];
    bf16x8 af[2], bd[2];
#pragma unroll
    for (int i = 0; i < 2; ++i) {
      int row = wr * 32 + i * 16 + lr;
      af[i] = *(const bf16x8*)&L[row * 32 + ((lgq ^ swz4(row)) * 8)];
    }
#pragma unroll
    for (int j = 0; j < 2; ++j) {
      int dr = wc * 32 + j * 16 + lr;
      bd[j] = *(const bf16x8*)&L[2048 + dr * 32 + ((lgq ^ swz4(dr)) * 8)];
    }
#pragma unroll
    for (int i = 0; i < 2; ++i)
#pragma unroll
      for (int j = 0; j < 2; ++j)
        acc[i][j] = __builtin_amdgcn_mfma_f32_16x16x32_bf16(af[i], bd[j], acc[i][j], 0, 0, 0);
  };

  STAGE(0, 0);
  asm volatile("s_waitcnt vmcnt(0)" ::: "memory");
  fence_barrier();
#pragma unroll 1
  for (int kt = 0; kt < NKT2; ++kt) {
    int cur = kt & 1;
    if (kt + 1 < NKT2) STAGE(cur ^ 1, kt + 1);
    COMPUTE(cur);
    if (kt + 1 < NKT2) asm volatile("s_waitcnt vmcnt(0)" ::: "memory");
    fence_barrier();
  }

#pragma unroll
  for (int i = 0; i < 2; ++i)
#pragma unroll
    for (int r = 0; r < 4; ++r) {
      int mrow = wr * 32 + i * 16 + lgq * 4 + r;
      if (mt * BM + mrow < cnt) {
        int slot = s0 + mrow;
        float wv = bw[slot];
#pragma unroll
        for (int j = 0; j < 2; ++j) {
          int col = n0 + wc * 32 + j * 16 + lr;
          Osl[(size_t)slot * DD + col] = (short)(cvtpk(acc[i][j][r] * wv, 0.f) & 0xffffu);
        }
      }
    }
}

// ---------------- combine: out[t] = x[t] + sum over 6 routed + 2 shared slots ----
__global__ __launch_bounds__(256) void combine_k(
    const short* __restrict__ Osl, const float* __restrict__ x,
    const int* __restrict__ tslot, float* __restrict__ out) {
  int wv = threadIdx.x >> 6, lane = threadIdx.x & 63;
  int t = blockIdx.x * 4 + wv;
  int d0 = lane * 8;
  const float* xp = x + (size_t)t * DD + d0;
  f32x4 sa = *(const f32x4*)xp;
  f32x4 sb = *(const f32x4*)(xp + 4);
  int slots[8];
#pragma unroll
  for (int k = 0; k < 6; ++k) slots[k] = tslot[t * TK + k];
  slots[6] = RSLOT + t;
  slots[7] = RSLOT + N_TOK + t;
#pragma unroll
  for (int k = 0; k < 8; ++k) {
    uint4 hv = *(const uint4*)&Osl[(size_t)slots[k] * DD + d0];
    unsigned u[4] = {hv.x, hv.y, hv.z, hv.w};
#pragma unroll
    for (int q = 0; q < 4; ++q) {
      float lo = __builtin_bit_cast(float, u[q] << 16);
      float hi = __builtin_bit_cast(float, u[q] & 0xffff0000u);
      if (q < 2) { sa[q * 2] += lo; sa[q * 2 + 1] += hi; }
      else { sb[(q - 2) * 2] += lo; sb[(q - 2) * 2 + 1] += hi; }
    }
  }
  float* op = out + (size_t)t * DD + d0;
  *(f32x4*)op = sa;
  *(f32x4*)(op + 4) = sb;
}

extern "C" void kernel_launch(void* const* d_in, const int* in_sizes, int n_in,
                              void* d_out, int out_size, void* d_ws, size_t ws_size,
                              hipStream_t stream) {
  const float* x   = (const float*)d_in[0];
  const float* Wr  = (const float*)d_in[1];
  const float* sWg = (const float*)d_in[2];
  const float* sWu = (const float*)d_in[3];
  const float* sWd = (const float*)d_in[4];
  const float* Wg  = (const float*)d_in[5];
  const float* Wu  = (const float*)d_in[6];
  const float* Wd  = (const float*)d_in[7];
  float* out = (float*)d_out;

  char* wsb = (char*)d_ws;
  size_t off = 0;
  short* Wt = (short*)(wsb + off);    off += (size_t)198 * MATSZ * 2;   // 99 MB bf16
  short* H  = (short*)(wsb + off);    off += (size_t)NSLOT * FF * 2;    // 16 MB
  short* Osl = (short*)(wsb + off);   off += (size_t)NSLOT * DD * 2;    // 16 MB
  short* Xb = (short*)(wsb + off);    off += (size_t)N_TOK * DD * 2;    // 2 MB
  int*   top_i = (int*)(wsb + off);   off += (size_t)RSLOT * 4;
  float* top_w = (float*)(wsb + off); off += (size_t)RSLOT * 4;
  int*   btok = (int*)(wsb + off);    off += (size_t)NSLOT * 4;
  float* bwt  = (float*)(wsb + off);  off += (size_t)NSLOT * 4;
  int*   tslot = (int*)(wsb + off);   off += (size_t)RSLOT * 4;
  int*   cnt  = (int*)(wsb + off);    off += 256;
  int*   fill = (int*)(wsb + off);    off += 256;
  int*   goff = (int*)(wsb + off);    off += 512;
  int*   wk_g = (int*)(wsb + off);    off += MAXT * 4;
  int*   wk_mt = (int*)(wsb + off);   off += MAXT * 4;
  int*   nitems = (int*)(wsb + off);  off += 256;

  const short* Wtg = Wt;
  const short* Wtu = Wt + (size_t)66 * MATSZ;
  const short* Wtd = Wt + (size_t)132 * MATSZ;

  hipMemsetAsync(cnt, 0, 256, stream);
  convw_k<<<dim3(128, 198), 256, 0, stream>>>(Wg, Wu, Wd, sWg, sWu, sWd, Wt);
  convx_k<<<512, 256, 0, stream>>>(x, Xb);
  router_k<<<N_TOK / 16, 256, 0, stream>>>(x, Wr, top_i, top_w, cnt);
  offsets_k<<<1, 64, 0, stream>>>(cnt, goff, fill, wk_g, wk_mt, nitems);
  scatter_k<<<NSLOT / 256, 256, 0, stream>>>(top_i, top_w, goff, fill, btok, bwt, tslot);
  dim3 grid1(FF / BN, MAXT, 1);
  gemm1_k<<<grid1, 256, 0, stream>>>(Xb, Wtg, Wtu, goff, btok, wk_g, wk_mt, nitems, H);
  dim3 grid2(DD / BN, MAXT, 1);
  gemm2_k<<<grid2, 256, 0, stream>>>(H, Wtd, goff, bwt, wk_g, wk_mt, nitems, Osl);
  combine_k<<<N_TOK / 4, 256, 0, stream>>>(Osl, x, tslot, out);
}

// Round 14
// 219.979 us; speedup vs baseline: 1.0013x; 1.0013x over previous
//
#include <hip/hip_runtime.h>

#define N_TOK 2048
#define DD 512
#define FF 512
#define EE 64
#define TK 6
#define NG 66
#define RSLOT 12288   // N_TOK*TK
#define NSLOT 16384   // RSLOT + 2*N_TOK
#define BM1 128       // gemm M-tile
#define NKT2 16       // 512/32 k-tiles (BK=32)
#define MAXT 192      // sum ceil(cnt_g/128) <= 160 + 32 shared
#define MATSZ 262144  // 512*512

typedef float f32x4 __attribute__((ext_vector_type(4)));
typedef __bf16 bf16x8 __attribute__((ext_vector_type(8)));

__device__ __forceinline__ unsigned cvtpk(float lo, float hi) {
  unsigned r;
  asm("v_cvt_pk_bf16_f32 %0, %1, %2" : "=v"(r) : "v"(lo), "v"(hi));
  return r;
}

__device__ __forceinline__ int swz4(int r) { return (r + (r >> 2)) & 3; }

// async global->LDS DMA, 16B/lane; dest = wave-uniform base + lane*16
__device__ __forceinline__ void gll16(const void* g, void* l) {
  __builtin_amdgcn_global_load_lds(
      (const __attribute__((address_space(1))) unsigned int*)g,
      (__attribute__((address_space(3))) unsigned int*)l, 16, 0, 0);
}

// ------- convert+transpose weights: gll16-staged, 4-tile dbuf pipeline ---------
// Block: one matrix, 64-d panel, 4 f-subtiles of 32. LDS linear [64][32] f32;
// bank fix via pre-swizzled SOURCE (key=(d>>3)&7 per gll16) + same XOR on read.
// Transpose reads 2-way max (free); dst writes 128B contiguous per 8 lanes.
__global__ __launch_bounds__(256) void convw_k(
    const float* __restrict__ Wg, const float* __restrict__ Wu, const float* __restrict__ Wd,
    const float* __restrict__ sWg, const float* __restrict__ sWu, const float* __restrict__ sWd,
    short* __restrict__ Wt) {
  __shared__ __align__(16) float B[2][2048];   // 2 x 8 KB
  int y = blockIdx.y;
  int kind = y / 66, idx = y % 66;
  const float* src;
  if (kind == 0)      src = (idx < EE) ? Wg + (size_t)idx * MATSZ : sWg + (size_t)(idx - EE) * MATSZ;
  else if (kind == 1) src = (idx < EE) ? Wu + (size_t)idx * MATSZ : sWu + (size_t)(idx - EE) * MATSZ;
  else                src = (idx < EE) ? Wd + (size_t)idx * MATSZ : sWd + (size_t)(idx - EE) * MATSZ;
  short* dst = Wt + (size_t)y * MATSZ;
  int d0 = (blockIdx.x & 7) * 64;
  int fp = (blockIdx.x >> 3) * 128;
  int t = threadIdx.x, lane = t & 63, w = t >> 6;

  // staging geometry (per wave, 2 gll16 per tile)
  int sd[2], su[2];
#pragma unroll
  for (int q = 0; q < 2; ++q) {
    sd[q] = w * 16 + q * 8 + (lane >> 3);          // source d row
    su[q] = (lane & 7) ^ (w * 2 + q);              // swizzled 16B unit
  }
  // transpose-read geometry
  int f = t >> 3, db = (t & 7) * 8;
  int elem = (((f >> 2) ^ (t & 7)) << 2) | (f & 3);

  auto STAGE = [&](int b, int ft) {
    int fb = fp + ft * 32;
#pragma unroll
    for (int q = 0; q < 2; ++q)
      gll16(src + (size_t)(d0 + sd[q]) * 512 + fb + su[q] * 4,
            &B[b][(w * 16 + q * 8) * 32]);
  };

  STAGE(0, 0);
#pragma unroll 1
  for (int ft = 0; ft < 4; ++ft) {
    int cur = ft & 1;
    if (ft + 1 < 4) {
      STAGE(cur ^ 1, ft + 1);
      asm volatile("s_waitcnt vmcnt(2)" ::: "memory");
    } else {
      asm volatile("s_waitcnt vmcnt(0)" ::: "memory");
    }
    __builtin_amdgcn_s_barrier();
    __builtin_amdgcn_sched_barrier(0);
    float v[8];
#pragma unroll
    for (int i = 0; i < 8; ++i) v[i] = B[cur][(db + i) * 32 + elem];
    uint4 o;
    o.x = cvtpk(v[0], v[1]); o.y = cvtpk(v[2], v[3]);
    o.z = cvtpk(v[4], v[5]); o.w = cvtpk(v[6], v[7]);
    *(uint4*)&dst[(size_t)(fp + ft * 32 + f) * 512 + d0 + db] = o;
    __builtin_amdgcn_s_barrier();
  }
}

// ------- convert X f32 -> bf16
__global__ void convx_k(const float* __restrict__ x, short* __restrict__ Xb) {
  int i = blockIdx.x * 256 + threadIdx.x;
  const f32x4* p = (const f32x4*)(x + (size_t)i * 8);
  f32x4 v0 = p[0], v1 = p[1];
  uint4 o;
  o.x = cvtpk(v0[0], v0[1]); o.y = cvtpk(v0[2], v0[3]);
  o.z = cvtpk(v1[0], v1[1]); o.w = cvtpk(v1[2], v1[3]);
  *(uint4*)&Xb[(size_t)i * 8] = o;
}

// ---------------- router ----------------
__global__ __launch_bounds__(256) void router_k(
    const float* __restrict__ x, const float* __restrict__ Wr,
    int* __restrict__ top_i, float* __restrict__ top_w, int* __restrict__ cnt) {
  __shared__ float xs[16 * 512];
  __shared__ float part[4][16][64];
  int tid = threadIdx.x, lane = tid & 63, w = tid >> 6;
  int t0 = blockIdx.x * 16;
  const f32x4* xin = (const f32x4*)(x + (size_t)t0 * DD);
  f32x4* xs4 = (f32x4*)xs;
#pragma unroll
  for (int i = 0; i < 8; ++i) xs4[i * 256 + tid] = xin[i * 256 + tid];
  __syncthreads();
  float acc[16];
#pragma unroll
  for (int t = 0; t < 16; ++t) acc[t] = 0.f;
  for (int kk = 0; kk < 32; ++kk) {
    int k = w * 128 + kk * 4;
    float w0 = Wr[(size_t)(k + 0) * EE + lane];
    float w1 = Wr[(size_t)(k + 1) * EE + lane];
    float w2 = Wr[(size_t)(k + 2) * EE + lane];
    float w3 = Wr[(size_t)(k + 3) * EE + lane];
#pragma unroll
    for (int t = 0; t < 16; ++t) {
      f32x4 xv = *(const f32x4*)&xs[t * 512 + k];
      acc[t] = fmaf(xv[0], w0, acc[t]);
      acc[t] = fmaf(xv[1], w1, acc[t]);
      acc[t] = fmaf(xv[2], w2, acc[t]);
      acc[t] = fmaf(xv[3], w3, acc[t]);
    }
  }
#pragma unroll
  for (int t = 0; t < 16; ++t) part[w][t][lane] = acc[t];
  __syncthreads();
#pragma unroll
  for (int tt = 0; tt < 4; ++tt) {
    int t = w * 4 + tt;
    float l0 = part[0][t][lane] + part[1][t][lane] + part[2][t][lane] + part[3][t][lane];
    float m = l0;
#pragma unroll
    for (int s = 32; s; s >>= 1) m = fmaxf(m, __shfl_xor(m, s));
    float p = __expf(l0 - m);
    int wi[TK]; float wv[TK];
#pragma unroll
    for (int it = 0; it < TK; ++it) {
      float v = p;
#pragma unroll
      for (int s = 32; s; s >>= 1) v = fmaxf(v, __shfl_xor(v, s));
      unsigned long long b = __ballot(p == v);
      int idx = __ffsll((unsigned long long)b) - 1;
      wi[it] = idx; wv[it] = v;
      if (lane == idx) p = -1.f;
    }
    float wsum = 0.f;
#pragma unroll
    for (int it = 0; it < TK; ++it) wsum += wv[it];
    int tg = t0 + t;
    if (lane < TK) {
      int si = 0; float sv = 0.f;
#pragma unroll
      for (int it = 0; it < TK; ++it) if (lane == it) { si = wi[it]; sv = wv[it]; }
      top_i[tg * TK + lane] = si;
      top_w[tg * TK + lane] = sv / wsum;
      atomicAdd(&cnt[si], 1);
    }
  }
}

// ---------------- offsets + dense work list (BM1=128 tiles) ----------------
__global__ void offsets_k(const int* __restrict__ cnt, int* __restrict__ goff,
                          int* __restrict__ fill, int* __restrict__ wk_g,
                          int* __restrict__ wk_mt, int* __restrict__ nitems) {
  int i = threadIdx.x;  // 0..63
  fill[i] = 0;
  int c = cnt[i];
  int s = c;
#pragma unroll
  for (int d = 1; d < 64; d <<= 1) { int t = __shfl_up(s, d); if (i >= d) s += t; }
  goff[i] = s - c;
  if (i == 63) {
    goff[EE] = RSLOT;
    goff[EE + 1] = RSLOT + N_TOK;
    goff[EE + 2] = RSLOT + 2 * N_TOK;
  }
  int nt = (c + BM1 - 1) >> 7;
  int ts = nt;
#pragma unroll
  for (int d = 1; d < 64; d <<= 1) { int t = __shfl_up(ts, d); if (i >= d) ts += t; }
  int texcl = ts - nt;
  for (int t = 0; t < nt; ++t) { wk_g[texcl + t] = i; wk_mt[texcl + t] = t; }
  int tot = __shfl(ts, 63);
  if (i < 32) {                       // shared groups: 2 x 16 tiles of 128
    wk_g[tot + i] = EE + (i >> 4);
    wk_mt[tot + i] = i & 15;
  }
  if (i == 0) nitems[0] = tot + 32;
}

// ---------------- scatter (also builds token->slot inverse map) ----------------
__global__ void scatter_k(const int* __restrict__ top_i, const float* __restrict__ top_w,
                          const int* __restrict__ goff, int* __restrict__ fill,
                          int* __restrict__ btok, float* __restrict__ bw,
                          int* __restrict__ tslot) {
  int idx = blockIdx.x * blockDim.x + threadIdx.x;
  if (idx < RSLOT) {
    int e = top_i[idx];
    int pos = goff[e] + atomicAdd(&fill[e], 1);
    btok[pos] = idx / TK;
    bw[pos] = top_w[idx];
    tslot[idx] = pos;
  } else if (idx < NSLOT) {
    int j = idx - RSLOT;
    btok[idx] = j & (N_TOK - 1);
    bw[idx] = 1.0f;
  }
}

// -------- GEMM1: H = silu(Xb*Wg)*(Xb*Wu). BM=128, BN=64, BK=32, dbuf. --------
__global__ __launch_bounds__(256) void gemm1_k(
    const short* __restrict__ Xb, const short* __restrict__ Wtg, const short* __restrict__ Wtu,
    const int* __restrict__ goff, const int* __restrict__ btok,
    const int* __restrict__ wk_g, const int* __restrict__ wk_mt,
    const int* __restrict__ nitems, short* __restrict__ H) {
  int item = blockIdx.y;
  if (item >= nitems[0]) return;
  int g = wk_g[item], mt = wk_mt[item];
  int s0g = goff[g], cnt = goff[g + 1] - s0g;
  if (mt * BM1 >= cnt) return;
  int n0 = blockIdx.x * 64;
  const short* gmat = Wtg + (size_t)g * MATSZ;
  const short* umat = Wtu + (size_t)g * MATSZ;

  // per buffer (shorts): A [0,4096) 128r x 32k; G [4096,6144) 64r; U [6144,8192)
  __shared__ __align__(16) short lds[2][8192];   // 32 KB

  int tid = threadIdx.x, lane = tid & 63, w = tid >> 6;
  int lr = lane & 15, lgq = lane >> 4;
  int s0 = s0g + mt * BM1;

  // staging: 16 chunks of 1KB/buf; wave w owns chunks w*4..w*4+3
  const short* sp[4];
  int ldst[4];
#pragma unroll
  for (int q = 0; q < 4; ++q) {
    int c = w * 4 + q;
    int rl, gu;
    if (c < 8) {
      rl = c * 16 + (lane >> 2);
      gu = (lane & 3) ^ swz4(rl);
      ldst[q] = c * 512;
      int slot = (mt * BM1 + rl < cnt) ? s0 + rl : s0;
      sp[q] = Xb + (size_t)btok[slot] * 512 + gu * 8;
    } else if (c < 12) {
      int cc = c - 8;
      rl = cc * 16 + (lane >> 2);
      gu = (lane & 3) ^ swz4(rl);
      ldst[q] = 4096 + cc * 512;
      sp[q] = gmat + (size_t)(n0 + rl) * 512 + gu * 8;
    } else {
      int cc = c - 12;
      rl = cc * 16 + (lane >> 2);
      gu = (lane & 3) ^ swz4(rl);
      ldst[q] = 6144 + cc * 512;
      sp[q] = umat + (size_t)(n0 + rl) * 512 + gu * 8;
    }
  }

  f32x4 accg[2][4], accu[2][4];
#pragma unroll
  for (int i = 0; i < 2; ++i)
#pragma unroll
    for (int j = 0; j < 4; ++j) {
      accg[i][j] = f32x4{0.f, 0.f, 0.f, 0.f};
      accu[i][j] = f32x4{0.f, 0.f, 0.f, 0.f};
    }

  auto STAGE = [&](int b, int kt) {
#pragma unroll
    for (int q = 0; q < 4; ++q) gll16(sp[q] + kt * 32, &lds[b][ldst[q]]);
  };
  auto COMPUTE = [&](int b) {
    const short* L = lds[b];
    bf16x8 af[2], bg[4], bu[4];
#pragma unroll
    for (int i = 0; i < 2; ++i) {
      int row = w * 32 + i * 16 + lr;
      af[i] = *(const bf16x8*)&L[row * 32 + ((lgq ^ swz4(row)) * 8)];
    }
#pragma unroll
    for (int j = 0; j < 4; ++j) {
      int fr = j * 16 + lr;
      int o = fr * 32 + ((lgq ^ swz4(fr)) * 8);
      bg[j] = *(const bf16x8*)&L[4096 + o];
      bu[j] = *(const bf16x8*)&L[6144 + o];
    }
#pragma unroll
    for (int i = 0; i < 2; ++i)
#pragma unroll
      for (int j = 0; j < 4; ++j) {
        accg[i][j] = __builtin_amdgcn_mfma_f32_16x16x32_bf16(af[i], bg[j], accg[i][j], 0, 0, 0);
        accu[i][j] = __builtin_amdgcn_mfma_f32_16x16x32_bf16(af[i], bu[j], accu[i][j], 0, 0, 0);
      }
  };

  STAGE(0, 0);
  asm volatile("s_waitcnt vmcnt(0)" ::: "memory");
  __builtin_amdgcn_s_barrier();
  __builtin_amdgcn_sched_barrier(0);
#pragma unroll 1
  for (int kt = 0; kt < NKT2; ++kt) {
    int cur = kt & 1;
    if (kt + 1 < NKT2) STAGE(cur ^ 1, kt + 1);
    COMPUTE(cur);
    asm volatile("s_waitcnt vmcnt(0)" ::: "memory");
    __builtin_amdgcn_s_barrier();
    __builtin_amdgcn_sched_barrier(0);
  }

#pragma unroll
  for (int i = 0; i < 2; ++i)
#pragma unroll
    for (int j = 0; j < 4; ++j)
#pragma unroll
      for (int r = 0; r < 4; ++r) {
        int mrow = w * 32 + i * 16 + lgq * 4 + r;
        if (mt * BM1 + mrow < cnt) {
          float gg = accg[i][j][r];
          float uu = accu[i][j][r];
          float hv = (gg / (1.f + __expf(-gg))) * uu;
          int col = n0 + j * 16 + lr;
          H[(size_t)(s0 + mrow) * FF + col] = (short)(cvtpk(hv, hv) & 0xffffu);
        }
      }
}

// -------- GEMM2: Osl[slot] = bw[slot]*(H[slot] x Wtd_g). BM=128, BN=64. -------
__global__ __launch_bounds__(256) void gemm2_k(
    const short* __restrict__ H, const short* __restrict__ Wtd,
    const int* __restrict__ goff, const float* __restrict__ bw,
    const int* __restrict__ wk_g, const int* __restrict__ wk_mt,
    const int* __restrict__ nitems, short* __restrict__ Osl) {
  int item = blockIdx.y;
  if (item >= nitems[0]) return;
  int g = wk_g[item], mt = wk_mt[item];
  int s0g = goff[g], cnt = goff[g + 1] - s0g;
  if (mt * BM1 >= cnt) return;
  int n0 = blockIdx.x * 64;
  const short* dmat = Wtd + (size_t)g * MATSZ;

  // per buffer (shorts): A(H) [0,4096); D [4096,6144)
  __shared__ __align__(16) short lds[2][6144];   // 24 KB

  int tid = threadIdx.x, lane = tid & 63, w = tid >> 6;
  int lr = lane & 15, lgq = lane >> 4;
  int s0 = s0g + mt * BM1;

  const short* sp[3];
  int ldst[3];
#pragma unroll
  for (int q = 0; q < 3; ++q) {
    int c = w * 3 + q;                // 0..11
    int rl, gu;
    if (c < 8) {
      rl = c * 16 + (lane >> 2);
      gu = (lane & 3) ^ swz4(rl);
      ldst[q] = c * 512;
      int slot = (mt * BM1 + rl < cnt) ? s0 + rl : s0;
      sp[q] = H + (size_t)slot * 512 + gu * 8;
    } else {
      int cc = c - 8;
      rl = cc * 16 + (lane >> 2);
      gu = (lane & 3) ^ swz4(rl);
      ldst[q] = 4096 + cc * 512;
      sp[q] = dmat + (size_t)(n0 + rl) * 512 + gu * 8;
    }
  }

  f32x4 acc[2][4];
#pragma unroll
  for (int i = 0; i < 2; ++i)
#pragma unroll
    for (int j = 0; j < 4; ++j) acc[i][j] = f32x4{0.f, 0.f, 0.f, 0.f};

  auto STAGE = [&](int b, int kt) {
#pragma unroll
    for (int q = 0; q < 3; ++q) gll16(sp[q] + kt * 32, &lds[b][ldst[q]]);
  };
  auto COMPUTE = [&](int b) {
    const short* L = lds[b];
    bf16x8 af[2], bd[4];
#pragma unroll
    for (int i = 0; i < 2; ++i) {
      int row = w * 32 + i * 16 + lr;
      af[i] = *(const bf16x8*)&L[row * 32 + ((lgq ^ swz4(row)) * 8)];
    }
#pragma unroll
    for (int j = 0; j < 4; ++j) {
      int dr = j * 16 + lr;
      bd[j] = *(const bf16x8*)&L[4096 + dr * 32 + ((lgq ^ swz4(dr)) * 8)];
    }
#pragma unroll
    for (int i = 0; i < 2; ++i)
#pragma unroll
      for (int j = 0; j < 4; ++j)
        acc[i][j] = __builtin_amdgcn_mfma_f32_16x16x32_bf16(af[i], bd[j], acc[i][j], 0, 0, 0);
  };

  STAGE(0, 0);
  asm volatile("s_waitcnt vmcnt(0)" ::: "memory");
  __builtin_amdgcn_s_barrier();
  __builtin_amdgcn_sched_barrier(0);
#pragma unroll 1
  for (int kt = 0; kt < NKT2; ++kt) {
    int cur = kt & 1;
    if (kt + 1 < NKT2) STAGE(cur ^ 1, kt + 1);
    COMPUTE(cur);
    asm volatile("s_waitcnt vmcnt(0)" ::: "memory");
    __builtin_amdgcn_s_barrier();
    __builtin_amdgcn_sched_barrier(0);
  }

#pragma unroll
  for (int i = 0; i < 2; ++i)
#pragma unroll
    for (int r = 0; r < 4; ++r) {
      int mrow = w * 32 + i * 16 + lgq * 4 + r;
      if (mt * BM1 + mrow < cnt) {
        int slot = s0 + mrow;
        float wv = bw[slot];
#pragma unroll
        for (int j = 0; j < 4; ++j) {
          int col = n0 + j * 16 + lr;
          Osl[(size_t)slot * DD + col] = (short)(cvtpk(acc[i][j][r] * wv, 0.f) & 0xffffu);
        }
      }
    }
}

// ---------------- combine: out[t] = x[t] + sum over 6 routed + 2 shared slots ----
__global__ __launch_bounds__(256) void combine_k(
    const short* __restrict__ Osl, const float* __restrict__ x,
    const int* __restrict__ tslot, float* __restrict__ out) {
  int wv = threadIdx.x >> 6, lane = threadIdx.x & 63;
  int t = blockIdx.x * 4 + wv;
  int d0 = lane * 8;
  const float* xp = x + (size_t)t * DD + d0;
  f32x4 sa = *(const f32x4*)xp;
  f32x4 sb = *(const f32x4*)(xp + 4);
  int slots[8];
#pragma unroll
  for (int k = 0; k < 6; ++k) slots[k] = tslot[t * TK + k];
  slots[6] = RSLOT + t;
  slots[7] = RSLOT + N_TOK + t;
#pragma unroll
  for (int k = 0; k < 8; ++k) {
    uint4 hv = *(const uint4*)&Osl[(size_t)slots[k] * DD + d0];
    unsigned u[4] = {hv.x, hv.y, hv.z, hv.w};
#pragma unroll
    for (int q = 0; q < 4; ++q) {
      float lo = __builtin_bit_cast(float, u[q] << 16);
      float hi = __builtin_bit_cast(float, u[q] & 0xffff0000u);
      if (q < 2) { sa[q * 2] += lo; sa[q * 2 + 1] += hi; }
      else { sb[(q - 2) * 2] += lo; sb[(q - 2) * 2 + 1] += hi; }
    }
  }
  float* op = out + (size_t)t * DD + d0;
  *(f32x4*)op = sa;
  *(f32x4*)(op + 4) = sb;
}

extern "C" void kernel_launch(void* const* d_in, const int* in_sizes, int n_in,
                              void* d_out, int out_size, void* d_ws, size_t ws_size,
                              hipStream_t stream) {
  const float* x   = (const float*)d_in[0];
  const float* Wr  = (const float*)d_in[1];
  const float* sWg = (const float*)d_in[2];
  const float* sWu = (const float*)d_in[3];
  const float* sWd = (const float*)d_in[4];
  const float* Wg  = (const float*)d_in[5];
  const float* Wu  = (const float*)d_in[6];
  const float* Wd  = (const float*)d_in[7];
  float* out = (float*)d_out;

  char* wsb = (char*)d_ws;
  size_t off = 0;
  short* Wt = (short*)(wsb + off);    off += (size_t)198 * MATSZ * 2;   // 99 MB bf16
  short* H  = (short*)(wsb + off);    off += (size_t)NSLOT * FF * 2;    // 16 MB
  short* Osl = (short*)(wsb + off);   off += (size_t)NSLOT * DD * 2;    // 16 MB
  short* Xb = (short*)(wsb + off);    off += (size_t)N_TOK * DD * 2;    // 2 MB
  int*   top_i = (int*)(wsb + off);   off += (size_t)RSLOT * 4;
  float* top_w = (float*)(wsb + off); off += (size_t)RSLOT * 4;
  int*   btok = (int*)(wsb + off);    off += (size_t)NSLOT * 4;
  float* bwt  = (float*)(wsb + off);  off += (size_t)NSLOT * 4;
  int*   tslot = (int*)(wsb + off);   off += (size_t)RSLOT * 4;
  int*   cnt  = (int*)(wsb + off);    off += 256;
  int*   fill = (int*)(wsb + off);    off += 256;
  int*   goff = (int*)(wsb + off);    off += 512;
  int*   wk_g = (int*)(wsb + off);    off += MAXT * 4;
  int*   wk_mt = (int*)(wsb + off);   off += MAXT * 4;
  int*   nitems = (int*)(wsb + off);  off += 256;

  const short* Wtg = Wt;
  const short* Wtu = Wt + (size_t)66 * MATSZ;
  const short* Wtd = Wt + (size_t)132 * MATSZ;

  hipMemsetAsync(cnt, 0, 256, stream);
  convw_k<<<dim3(32, 198), 256, 0, stream>>>(Wg, Wu, Wd, sWg, sWu, sWd, Wt);
  convx_k<<<512, 256, 0, stream>>>(x, Xb);
  router_k<<<N_TOK / 16, 256, 0, stream>>>(x, Wr, top_i, top_w, cnt);
  offsets_k<<<1, 64, 0, stream>>>(cnt, goff, fill, wk_g, wk_mt, nitems);
  scatter_k<<<NSLOT / 256, 256, 0, stream>>>(top_i, top_w, goff, fill, btok, bwt, tslot);
  dim3 grid1(FF / 64, MAXT, 1);
  gemm1_k<<<grid1, 256, 0, stream>>>(Xb, Wtg, Wtu, goff, btok, wk_g, wk_mt, nitems, H);
  dim3 grid2(DD / 64, MAXT, 1);
  gemm2_k<<<grid2, 256, 0, stream>>>(H, Wtd, goff, bwt, wk_g, wk_mt, nitems, Osl);
  combine_k<<<N_TOK / 4, 256, 0, stream>>>(Osl, x, tslot, out);
}